// Round 1
// 1442.271 us; speedup vs baseline: 1.1180x; 1.1180x over previous
//
#include <hip/hip_runtime.h>
#include <cstdint>
#include <cstddef>

typedef __attribute__((ext_vector_type(4))) float f32x4;
typedef __attribute__((ext_vector_type(8))) short s16x8;

#define MFMA16(a, b, c) __builtin_amdgcn_mfma_f32_16x16x32_bf16(a, b, c, 0, 0, 0)

// Split fp32 into bf16 hi + bf16 lo (truncation; residual < 2^-17 * |f|).
__device__ __forceinline__ void bsplit(float f, unsigned short& h, unsigned short& l) {
  unsigned u = __float_as_uint(f);
  h = (unsigned short)(u >> 16);
  float hf = __uint_as_float(u & 0xffff0000u);
  l = (unsigned short)(__float_as_uint(f - hf) >> 16);
}

// ---- GEMM: out[m][n] += sum_k A[m][k]*W[n][k], M=128, N=2048, split-K grid.y ----
// T14 async-stage: global float4 loads for step s+1 are issued right after the
// first barrier of step s, so HBM streaming overlaps the 48 MFMAs.

__device__ __forceinline__ void load_tile(const float* __restrict__ base, int D, int k,
                                          int tid, float4* r) {
#pragma unroll
  for (int v = 0; v < 4; ++v) {
    int flat = v * 256 + tid;      // 0..1023 ; 8 float4 per 32-col row
    int row = flat >> 3, kq = flat & 7;
    r[v] = *(const float4*)(base + (size_t)row * D + k + kq * 4);
  }
}

__device__ __forceinline__ void write_tile(const float4* r, unsigned short* ldsH,
                                           unsigned short* ldsL, int tid) {
#pragma unroll
  for (int v = 0; v < 4; ++v) {
    int flat = v * 256 + tid;
    int row = flat >> 3, kq = flat & 7;
    float4 f = r[v];
    ushort4 hh, ll;
    bsplit(f.x, hh.x, ll.x);
    bsplit(f.y, hh.y, ll.y);
    bsplit(f.z, hh.z, ll.z);
    bsplit(f.w, hh.w, ll.w);
    *(ushort4*)&ldsH[row * 40 + kq * 4] = hh;   // stride 40 ushort: bank-safe
    *(ushort4*)&ldsL[row * 40 + kq * 4] = ll;
  }
}

__global__ __launch_bounds__(256, 2) void k_gemm(const float* __restrict__ A,
                                                 const float* __restrict__ W,
                                                 float* __restrict__ out,
                                                 int D, int stepsPerChunk) {
  __shared__ __align__(16) unsigned short Ah[128 * 40], Al[128 * 40];
  __shared__ __align__(16) unsigned short Bh[128 * 40], Bl[128 * 40];
  const int tid = threadIdx.x;
  const int n0 = blockIdx.x * 128;
  const int totalSteps = D >> 5;
  const int s0 = blockIdx.y * stepsPerChunk;
  const int s1 = (s0 + stepsPerChunk < totalSteps) ? s0 + stepsPerChunk : totalSteps;
  const int wave = tid >> 6, lane = tid & 63;
  const int q = lane >> 4, li = lane & 15;
  const int wm = (wave >> 1) * 64, wn = (wave & 1) * 64;
  const float* bbase = W + (size_t)n0 * D;

  f32x4 acc[4][4] = {};
  float4 pa[4], pb[4];
  load_tile(A, D, s0 << 5, tid, pa);
  load_tile(bbase, D, s0 << 5, tid, pb);

  for (int s = s0; s < s1; ++s) {
    write_tile(pa, Ah, Al, tid);
    write_tile(pb, Bh, Bl, tid);
    __syncthreads();
    if (s + 1 < s1) {                      // prefetch next tile under the MFMAs
      load_tile(A, D, (s + 1) << 5, tid, pa);
      load_tile(bbase, D, (s + 1) << 5, tid, pb);
    }

    s16x8 a_h[4], a_l[4], b_h[4], b_l[4];
#pragma unroll
    for (int mt = 0; mt < 4; ++mt) {
      int m = wm + mt * 16 + li;
      a_h[mt] = *(const s16x8*)&Ah[m * 40 + q * 8];
      a_l[mt] = *(const s16x8*)&Al[m * 40 + q * 8];
    }
#pragma unroll
    for (int nt = 0; nt < 4; ++nt) {
      int n = wn + nt * 16 + li;
      b_h[nt] = *(const s16x8*)&Bh[n * 40 + q * 8];
      b_l[nt] = *(const s16x8*)&Bl[n * 40 + q * 8];
    }
#pragma unroll
    for (int mt = 0; mt < 4; ++mt)
#pragma unroll
      for (int nt = 0; nt < 4; ++nt) {
        acc[mt][nt] = MFMA16(a_h[mt], b_h[nt], acc[mt][nt]);
        acc[mt][nt] = MFMA16(a_h[mt], b_l[nt], acc[mt][nt]);
        acc[mt][nt] = MFMA16(a_l[mt], b_h[nt], acc[mt][nt]);
      }
    __syncthreads();
  }

#pragma unroll
  for (int mt = 0; mt < 4; ++mt)
#pragma unroll
    for (int nt = 0; nt < 4; ++nt)
#pragma unroll
      for (int r = 0; r < 4; ++r) {
        int m = wm + mt * 16 + q * 4 + r;
        int n = n0 + wn + nt * 16 + li;
        atomicAdd(&out[m * 2048 + n], acc[mt][nt][r]);
      }
}

// ---- Fused recurrence: layer0 + (Wih1 gemm) + layer1, cross-layer pipelined ----
// 64 blocks x 256 threads. Blocks 0..31 = layer 0, 32..63 = layer 1.
// Layer-1 blocks hold BOTH Wih1 and Whh1 bf16 hi/lo fragments in VGPRs and
// compute Wih1*h0_t + Whh1*h1_{t-1} per step; they gate on layer-0's per-step
// counter, so layer-1 step t overlaps layer-0 step t+1 (serial depth 33 -> ~17).

__device__ __forceinline__ void load_wfrags(const float* __restrict__ W, int row, int q,
                                            s16x8* wh, s16x8* wl) {
#pragma unroll
  for (int ks = 0; ks < 16; ++ks) {
    float fv[8];
    *(float4*)&fv[0] = *(const float4*)(W + row * 512 + ks * 32 + q * 8);
    *(float4*)&fv[4] = *(const float4*)(W + row * 512 + ks * 32 + q * 8 + 4);
    s16x8 h8, l8;
#pragma unroll
    for (int j = 0; j < 8; ++j) {
      unsigned short h, l;
      bsplit(fv[j], h, l);
      h8[j] = (short)h;
      l8[j] = (short)l;
    }
    wh[ks] = h8;
    wl[ks] = l8;
  }
}

// Stage h[b][t][:] (8x512 fp32) into bf16 hi/lo A-tile (rows 8..15 stay zero).
__device__ __forceinline__ void stage_h(const float* __restrict__ src, int t,
                                        unsigned short* Ah, unsigned short* Al, int tid) {
#pragma unroll
  for (int v = 0; v < 4; ++v) {
    int flat = v * 256 + tid;   // 0..1023 ; 128 float4 per batch row
    int b = flat >> 7, kq = flat & 127;
    float4 f = *(const float4*)(src + (b * 16 + t) * 512 + kq * 4);
    ushort4 hh, ll;
    bsplit(f.x, hh.x, ll.x);
    bsplit(f.y, hh.y, ll.y);
    bsplit(f.z, hh.z, ll.z);
    bsplit(f.w, hh.w, ll.w);
    *(ushort4*)&Ah[b * 520 + kq * 4] = hh;
    *(ushort4*)&Al[b * 520 + kq * 4] = ll;
  }
}

__device__ __forceinline__ f32x4 mac_tile(const unsigned short* Ah, const unsigned short* Al,
                                          const s16x8* wh, const s16x8* wl,
                                          int li, int q, f32x4 acc) {
#pragma unroll
  for (int ks = 0; ks < 16; ++ks) {
    s16x8 ah = *(const s16x8*)&Ah[li * 520 + ks * 32 + q * 8];
    s16x8 al = *(const s16x8*)&Al[li * 520 + ks * 32 + q * 8];
    acc = MFMA16(ah, wh[ks], acc);
    acc = MFMA16(ah, wl[ks], acc);
    acc = MFMA16(al, wh[ks], acc);
  }
  return acc;
}

__global__ __launch_bounds__(256, 1) void k_rec2(
    const float* __restrict__ xg0,
    const float* __restrict__ Whh0,
    const float* __restrict__ bih0, const float* __restrict__ bhh0,
    const float* __restrict__ Wih1, const float* __restrict__ Whh1,
    const float* __restrict__ bih1, const float* __restrict__ bhh1,
    float* __restrict__ h0_all, float* __restrict__ h1_all,
    int* __restrict__ cnt0, int* __restrict__ cnt1) {
  __shared__ __align__(16) unsigned short A0h[16 * 520], A0l[16 * 520];
  __shared__ __align__(16) unsigned short A1h[16 * 520], A1l[16 * 520];
  const int tid = threadIdx.x;
  const int lane = tid & 63, wave = tid >> 6;
  const int q = lane >> 4, li = lane & 15;
  const int g = li >> 2, jj = li & 3;
  const int layer = blockIdx.x >> 5;
  const int blk = blockIdx.x & 31;
  const int wgl = blk * 4 + wave;          // 0..127 within the layer
  const int j0 = wgl * 4;
  const int row = g * 512 + j0 + jj;       // W / bias / gate row for this lane

  for (int i = tid; i < 16 * 520; i += 256) {
    A0h[i] = 0; A0l[i] = 0; A1h[i] = 0; A1l[i] = 0;
  }

  s16x8 wh[16], wl[16];                    // Whh fragments (both layers)
  load_wfrags(layer ? Whh1 : Whh0, row, q, wh, wl);
  s16x8 uh[16], ul[16];                    // Wih1 fragments (layer 1 only)
  if (layer) load_wfrags(Wih1, row, q, uh, ul);
  const float bias = layer ? (bih1[row] + bhh1[row]) : (bih0[row] + bhh0[row]);
  float c[4] = {0.f, 0.f, 0.f, 0.f};
  __syncthreads();

  if (layer == 0) {
    for (int t = 0; t < 16; ++t) {
      if (t > 0) {
        if (tid == 0) {
          while (__hip_atomic_load(cnt0 + (t - 1), __ATOMIC_ACQUIRE,
                                   __HIP_MEMORY_SCOPE_AGENT) < 32) {}
        }
        __syncthreads();
        stage_h(h0_all, t - 1, A0h, A0l, tid);
        __syncthreads();
      }

      f32x4 acc = {0.f, 0.f, 0.f, 0.f};
      if (t > 0) acc = mac_tile(A0h, A0l, wh, wl, li, q, acc);

      float val[4];
#pragma unroll
      for (int r = 0; r < 4; ++r) {
        int mrow = q * 4 + r;
        float pre = acc[r] + bias;
        if (mrow < 8) pre += xg0[(mrow * 16 + t) * 2048 + row];
        val[r] = (g == 2) ? tanhf(pre) : 1.f / (1.f + __expf(-pre));
      }
      const int base = lane & 48;
#pragma unroll
      for (int r = 0; r < 4; ++r) {
        float iv = __shfl(val[r], base + 0 + jj);
        float fv = __shfl(val[r], base + 4 + jj);
        float gv = __shfl(val[r], base + 8 + jj);
        float ov = __shfl(val[r], base + 12 + jj);
        int mrow = q * 4 + r;
        if (g == 0 && mrow < 8) {
          c[r] = fv * c[r] + iv * gv;
          h0_all[(mrow * 16 + t) * 512 + j0 + jj] = ov * tanhf(c[r]);
        }
      }

      __threadfence();
      __syncthreads();
      if (tid == 0)
        __hip_atomic_fetch_add(cnt0 + t, 1, __ATOMIC_RELEASE, __HIP_MEMORY_SCOPE_AGENT);
    }
  } else {
    for (int t = 0; t < 16; ++t) {
      if (tid == 0) {
        while (__hip_atomic_load(cnt0 + t, __ATOMIC_ACQUIRE,
                                 __HIP_MEMORY_SCOPE_AGENT) < 32) {}
        if (t > 0) {
          while (__hip_atomic_load(cnt1 + (t - 1), __ATOMIC_ACQUIRE,
                                   __HIP_MEMORY_SCOPE_AGENT) < 32) {}
        }
      }
      __syncthreads();
      stage_h(h0_all, t, A0h, A0l, tid);
      if (t > 0) stage_h(h1_all, t - 1, A1h, A1l, tid);
      __syncthreads();

      f32x4 acc = {0.f, 0.f, 0.f, 0.f};
      acc = mac_tile(A0h, A0l, uh, ul, li, q, acc);           // Wih1 * h0_t
      if (t > 0) acc = mac_tile(A1h, A1l, wh, wl, li, q, acc); // Whh1 * h1_{t-1}

      float val[4];
#pragma unroll
      for (int r = 0; r < 4; ++r) {
        float pre = acc[r] + bias;
        val[r] = (g == 2) ? tanhf(pre) : 1.f / (1.f + __expf(-pre));
      }
      const int base = lane & 48;
#pragma unroll
      for (int r = 0; r < 4; ++r) {
        float iv = __shfl(val[r], base + 0 + jj);
        float fv = __shfl(val[r], base + 4 + jj);
        float gv = __shfl(val[r], base + 8 + jj);
        float ov = __shfl(val[r], base + 12 + jj);
        int mrow = q * 4 + r;
        if (g == 0 && mrow < 8) {
          c[r] = fv * c[r] + iv * gv;
          h1_all[(mrow * 16 + t) * 512 + j0 + jj] = ov * tanhf(c[r]);
        }
      }

      if (t < 15) {
        __threadfence();
        __syncthreads();
        if (tid == 0)
          __hip_atomic_fetch_add(cnt1 + t, 1, __ATOMIC_RELEASE, __HIP_MEMORY_SCOPE_AGENT);
      }
    }
  }
}

__global__ void k_fc(const float* __restrict__ h_all, const float* __restrict__ fw,
                     const float* __restrict__ fb, float* __restrict__ out) {
  int b = blockIdx.x / 6, o = blockIdx.x % 6;
  int lane = threadIdx.x;
  const float* h = h_all + (b * 16 + 15) * 512;
  float s = 0.f;
  for (int j = lane; j < 512; j += 64) s += h[j] * fw[o * 512 + j];
#pragma unroll
  for (int off = 32; off; off >>= 1) s += __shfl_down(s, off);
  if (lane == 0) out[b * 6 + o] = s + fb[o];
}

extern "C" void kernel_launch(void* const* d_in, const int* in_sizes, int n_in,
                              void* d_out, int out_size, void* d_ws, size_t ws_size,
                              hipStream_t stream) {
  const float* x    = (const float*)d_in[0];
  const float* Wih0 = (const float*)d_in[1];
  const float* Whh0 = (const float*)d_in[2];
  const float* bih0 = (const float*)d_in[3];
  const float* bhh0 = (const float*)d_in[4];
  const float* Wih1 = (const float*)d_in[5];
  const float* Whh1 = (const float*)d_in[6];
  const float* bih1 = (const float*)d_in[7];
  const float* bhh1 = (const float*)d_in[8];
  const float* fcw  = (const float*)d_in[9];
  const float* fcb  = (const float*)d_in[10];
  float* out = (float*)d_out;

  char* ws = (char*)d_ws;
  size_t off = 0;
  auto alloc = [&](size_t bytes) -> void* {
    void* p = ws + off;
    off += (bytes + 255) & ~(size_t)255;
    return p;
  };
  float* xg0 = (float*)alloc(128 * 2048 * sizeof(float));  // 1 MB, atomic-accumulated
  int* cnt   = (int*)alloc(4096);                          // cnt0[16], cnt1[16]
  const size_t zeroBytes = off;                            // zeroed each call
  float* h0 = (float*)alloc(128 * 512 * sizeof(float));    // [B][T][H]
  float* h1 = (float*)alloc(128 * 512 * sizeof(float));
  (void)ws_size; (void)in_sizes; (void)n_in; (void)out_size;

  hipMemsetAsync(d_ws, 0, zeroBytes, stream);

  // Layer 0 input GEMM: xg0 = x @ W_ih0^T (K = 113344 = 3542 k-steps; 77 x 46)
  k_gemm<<<dim3(16, 77), 256, 0, stream>>>(x, Wih0, xg0, 113344, 46);

  // Fused pipelined recurrence: rec0 + (Wih1 gemm) + rec1
  k_rec2<<<64, 256, 0, stream>>>(xg0, Whh0, bih0, bhh0, Wih1, Whh1, bih1, bhh1,
                                 h0, h1, cnt, cnt + 16);

  k_fc<<<48, 64, 0, stream>>>(h1, fcw, fcb, out);
}